// Round 8
// baseline (163.946 us; speedup 1.0000x reference)
//
#include <hip/hip_runtime.h>

#define F_DIMC 64
#define K_DIMC 16
#define NGRAPH 64
#define NXCD 8
#define ADJ_SPLIT 32
#define SX_SPLIT 16
#define NB_SEL 400                         // N/256
#define NB_HIST 256
#define ADJ_BLOCKS (ADJ_SPLIT * NGRAPH)    // 2048
#define SX_BLOCKS (SX_SPLIT * NGRAPH)      // 1024
#define ADJ_OFF (NGRAPH * K_DIMC * F_DIMC)
#define LOSS_OFF (ADJ_OFF + NGRAPH * K_DIMC * K_DIMC)

// ---------------- workspace layout (bytes) ----------------
// zeroed each call: [0, 394496)
//   [0,256)          hist (int[64])
//   [256,512)        cursor (int[64])
//   [512,768)        den (float[64])
//   [768,1024)       donecnt (int) + pad
//   [1024,66560)     dense_raw (float[64*256])
//   [66560,132096)   ssbuf (float[64*256])
//   [132096,394240)  sxbuf (float[64*1024])
//   [394240,394496)  loss (float[2]) + pad
// not zeroed:
//   [394496,394752)    offsets (int[64])   (written by scatter block 0 each call)
//   [394752,6948352)   sel (float[N*16])
//   [6948352,7357952)  q (float[N])
//   [7357952,13911552) sorted (uint2[E])

// ---- fused: selection (blocks [0,NB_SEL)) || edge count histogram (rest) ----
__global__ __launch_bounds__(256) void k_sel_hist(const float* __restrict__ node_attr,
                                                  const float* __restrict__ W,
                                                  const float* __restrict__ bias,
                                                  const int* __restrict__ row,
                                                  float* __restrict__ sel,
                                                  float* __restrict__ q,
                                                  int* __restrict__ hist,
                                                  int N, int E4, int perG) {
    __shared__ float sW[K_DIMC][F_DIMC];
    __shared__ float sb[K_DIMC];
    __shared__ int lh[NGRAPH];
    int t = threadIdx.x;
    if (blockIdx.x < NB_SEL) {
        for (int idx = t; idx < F_DIMC * K_DIMC; idx += 256) {
            int f = idx / K_DIMC, k = idx % K_DIMC;
            sW[k][f] = W[idx];
        }
        if (t < K_DIMC) sb[t] = bias[t];
        __syncthreads();
        int n = blockIdx.x * 256 + t;
        if (n >= N) return;

        const float4* xr = (const float4*)(node_attr + (size_t)n * F_DIMC);
        float4 x[F_DIMC / 4];
#pragma unroll
        for (int f4 = 0; f4 < F_DIMC / 4; ++f4) x[f4] = xr[f4];

        float logits[K_DIMC];
#pragma unroll
        for (int k = 0; k < K_DIMC; ++k) {
            const float4* wk = (const float4*)&sW[k][0];
            float acc = sb[k];
#pragma unroll
            for (int f4 = 0; f4 < F_DIMC / 4; ++f4) {
                float4 w = wk[f4];
                acc += x[f4].x * w.x + x[f4].y * w.y + x[f4].z * w.z + x[f4].w * w.w;
            }
            logits[k] = acc;
        }
        float m = logits[0];
#pragma unroll
        for (int k = 1; k < K_DIMC; ++k) m = fmaxf(m, logits[k]);
        float sum = 0.f;
#pragma unroll
        for (int k = 0; k < K_DIMC; ++k) {
            float e = __expf(logits[k] - m);
            logits[k] = e;
            sum += e;
        }
        float inv = 1.f / sum;
        float qq = 0.f;
        float4* sd = (float4*)(sel + (size_t)n * K_DIMC);
#pragma unroll
        for (int k4 = 0; k4 < K_DIMC / 4; ++k4) {
            float4 v;
            v.x = logits[4 * k4 + 0] * inv;
            v.y = logits[4 * k4 + 1] * inv;
            v.z = logits[4 * k4 + 2] * inv;
            v.w = logits[4 * k4 + 3] * inv;
            qq += v.x * v.x + v.y * v.y + v.z * v.z + v.w * v.w;
            sd[k4] = v;
        }
        q[n] = qq;
    } else {
        if (t < NGRAPH) lh[t] = 0;
        __syncthreads();
        for (int e4 = (blockIdx.x - NB_SEL) * 256 + t; e4 < E4; e4 += NB_HIST * 256) {
            int4 r4 = ((const int4*)row)[e4];
            atomicAdd(&lh[r4.x / perG], 1);
            atomicAdd(&lh[r4.y / perG], 1);
            atomicAdd(&lh[r4.z / perG], 1);
            atomicAdd(&lh[r4.w / perG], 1);
        }
        __syncthreads();
        if (t < NGRAPH) {
            int c = lh[t];
            if (c) atomicAdd(&hist[t], c);
        }
    }
}

// ---- scatter with in-block scan of hist (kills k_scan) + den = sum_e q[row_e] ----
__global__ __launch_bounds__(512) void k_scatter(const int* __restrict__ row,
                                                 const int* __restrict__ col,
                                                 const float* __restrict__ q,
                                                 const int* __restrict__ hist,
                                                 int* __restrict__ cursor,
                                                 int* __restrict__ offsets,
                                                 float* __restrict__ den,
                                                 uint2* __restrict__ sorted,
                                                 int E, int perG) {
    __shared__ int offs[NGRAPH];
    __shared__ int lcnt[NGRAPH];
    __shared__ int lbase[NGRAPH];
    __shared__ float lden[NGRAPH];
    int t = threadIdx.x;
    if (t < 64) {
        int v = hist[t];
        int sum = v;
#pragma unroll
        for (int d = 1; d < 64; d <<= 1) {
            int o = __shfl_up(sum, d);
            if (t >= d) sum += o;
        }
        offs[t] = sum - v;
        lcnt[t] = 0;
        lden[t] = 0.f;
        if (blockIdx.x == 0) offsets[t] = sum - v;
    }
    __syncthreads();
    int e = blockIdx.x * blockDim.x + t;
    int r = 0, c = 0, g = 0, lpos = 0;
    bool valid = e < E;
    if (valid) {
        r = row[e];
        c = col[e];
        g = r / perG;
        lpos = atomicAdd(&lcnt[g], 1);
        atomicAdd(&lden[g], q[r]);
    }
    __syncthreads();
    if (t < NGRAPH) {
        int cnt = lcnt[t];
        if (cnt) {
            lbase[t] = offs[t] + atomicAdd(&cursor[t], cnt);
            atomicAdd(&den[t], lden[t]);
        }
    }
    __syncthreads();
    if (valid) {
        sorted[(size_t)lbase[g] + lpos] = make_uint2((unsigned)r, (unsigned)c);
    }
}

// ---- fused: adj (blocks [0,2048), XCD-grouped) || SX/SS (blocks [2048,3072)) ----
__global__ __launch_bounds__(256) void k_adj_sx(const uint2* __restrict__ sorted,
                                                const int* __restrict__ offsets,
                                                const int* __restrict__ hist,
                                                const float* __restrict__ sel,
                                                const float* __restrict__ x,
                                                float* __restrict__ dense_raw,
                                                float* __restrict__ ssbuf,
                                                float* __restrict__ sxbuf,
                                                int perG) {
    __shared__ float lacc[4][256];
    __shared__ float lsx[4][K_DIMC * F_DIMC];
    __shared__ float lss[4][256];
    int b = blockIdx.x;
    int t = threadIdx.x;
    int wid = t >> 6;
    int lane = t & 63;
    if (b < ADJ_BLOCKS) {
        // graph g's 32 blocks all on XCD b&7 -> its sel slice stays in that L2
        int xcd = b & (NXCD - 1);
        int idx = b >> 3;
        int g = xcd * (NGRAPH / NXCD) + (idx >> 5);
        int split = idx & (ADJ_SPLIT - 1);

        int start = offsets[g];
        int cnt = hist[g];
        int wavesPerGraph = ADJ_SPLIT * 4;
        int wseq = split * 4 + wid;
        int i = lane >> 2;
        int j0 = (lane & 3) * 4;

        int chunk = (cnt + wavesPerGraph - 1) / wavesPerGraph;
        int myStart = start + wseq * chunk;
        int myEnd = start + cnt;
        if (myStart + chunk < myEnd) myEnd = myStart + chunk;

        float ax = 0.f, ay = 0.f, az = 0.f, aw = 0.f;
        for (int r0 = myStart; r0 < myEnd; r0 += 64) {
            int nb = myEnd - r0;
            if (nb > 64) nb = 64;
            uint2 pr = sorted[r0 + (lane < nb ? lane : nb - 1)];
            int rx = (int)pr.x * K_DIMC;
            int cx = (int)pr.y * K_DIMC;
#pragma unroll 8
            for (int ee = 0; ee < nb; ++ee) {
                int rb = __builtin_amdgcn_readlane(rx, ee);
                int cb = __builtin_amdgcn_readlane(cx, ee);
                float a = sel[rb + i];
                float4 bv = *(const float4*)(sel + cb + j0);
                ax = fmaf(a, bv.x, ax);
                ay = fmaf(a, bv.y, ay);
                az = fmaf(a, bv.z, az);
                aw = fmaf(a, bv.w, aw);
            }
        }
        *(float4*)&lacc[wid][i * K_DIMC + j0] = make_float4(ax, ay, az, aw);
        __syncthreads();
        float s = lacc[0][t] + lacc[1][t] + lacc[2][t] + lacc[3][t];
        atomicAdd(dense_raw + g * 256 + t, s);
    } else {
        int sxb = b - ADJ_BLOCKS;           // 0..1023
        int xcd = sxb & (NXCD - 1);
        int rem = sxb >> 3;                 // 0..127
        int g = xcd * (NGRAPH / NXCD) + (rem >> 4);
        int split = rem & (SX_SPLIT - 1);
        int wslot = split * 4 + wid;        // 0..63
        int k = lane >> 2;
        int sub = lane & 3;
        int f0 = sub * 16;
        int j0 = sub * 4;
        float accss[4] = {0.f, 0.f, 0.f, 0.f};
        float accsx[16];
#pragma unroll
        for (int j = 0; j < 16; ++j) accsx[j] = 0.f;
        size_t base = (size_t)g * perG;
#pragma unroll 2
        for (int nn = wslot; nn < perG; nn += SX_SPLIT * 4) {
            size_t node = base + nn;
            float a = sel[node * K_DIMC + k];
            float4 s4 = *(const float4*)(sel + node * K_DIMC + j0);
            accss[0] += a * s4.x;
            accss[1] += a * s4.y;
            accss[2] += a * s4.z;
            accss[3] += a * s4.w;
            const float4* xv = (const float4*)(x + node * F_DIMC + f0);
#pragma unroll
            for (int j = 0; j < 4; ++j) {
                float4 v = xv[j];
                accsx[4 * j + 0] += a * v.x;
                accsx[4 * j + 1] += a * v.y;
                accsx[4 * j + 2] += a * v.z;
                accsx[4 * j + 3] += a * v.w;
            }
        }
#pragma unroll
        for (int j4 = 0; j4 < 4; ++j4) {
            *(float4*)&lsx[wid][k * F_DIMC + f0 + 4 * j4] =
                make_float4(accsx[4 * j4], accsx[4 * j4 + 1], accsx[4 * j4 + 2], accsx[4 * j4 + 3]);
        }
        *(float4*)&lss[wid][k * K_DIMC + j0] = make_float4(accss[0], accss[1], accss[2], accss[3]);
        __syncthreads();
        for (int c2 = t; c2 < K_DIMC * F_DIMC; c2 += 256) {
            float s = lsx[0][c2] + lsx[1][c2] + lsx[2][c2] + lsx[3][c2];
            atomicAdd(sxbuf + (size_t)g * (K_DIMC * F_DIMC) + c2, s);
        }
        {
            float s = lss[0][t] + lss[1][t] + lss[2][t] + lss[3][t];
            atomicAdd(ssbuf + g * 256 + t, s);
        }
    }
}

// ---- finalize: normalize adj, copy SX to out, losses via ws + last-block write ----
__global__ __launch_bounds__(256) void k_fin(const float* __restrict__ dense_raw,
                                             const float* __restrict__ ssbuf,
                                             const float* __restrict__ sxbuf,
                                             const float* __restrict__ den,
                                             float* __restrict__ lossws,
                                             int* __restrict__ donecnt,
                                             float* __restrict__ out) {
    int g = blockIdx.x;
    int c = threadIdx.x;
    int k = c >> 4, j = c & 15;
    int lane = threadIdx.x & 63;
    int wid = threadIdx.x >> 6;

    // copy SX tile (sole writer of out's SX region)
    ((float4*)(out + (size_t)g * (K_DIMC * F_DIMC)))[c] =
        ((const float4*)(sxbuf + (size_t)g * (K_DIMC * F_DIMC)))[c];

    float a = dense_raw[g * 256 + c];
    float s = a;
    s += __shfl_xor(s, 1);
    s += __shfl_xor(s, 2);
    s += __shfl_xor(s, 4);
    s += __shfl_xor(s, 8);
    __shared__ float dvrow[K_DIMC];
    if (j == 0) dvrow[k] = sqrtf(s) + 1e-15f;
    __syncthreads();
    float v = a / (dvrow[k] * dvrow[j]);
    out[ADJ_OFF + g * 256 + c] = v;

    float ss = ssbuf[g * 256 + c];
    float tt = (k == j) ? v : 0.f;
    float n2 = ss * ss;
#pragma unroll
    for (int off = 32; off > 0; off >>= 1) {
        tt += __shfl_down(tt, off);
        n2 += __shfl_down(n2, off);
    }
    __shared__ float redt[4], redn[4];
    if (lane == 0) { redt[wid] = tt; redn[wid] = n2; }
    __syncthreads();
    float tr = redt[0] + redt[1] + redt[2] + redt[3];
    float nrm2 = redn[0] + redn[1] + redn[2] + redn[3];
    float invn = 1.f / sqrtf(nrm2);
    float d = ss * invn - ((k == j) ? 0.25f : 0.f);
    float o2 = d * d;
#pragma unroll
    for (int off = 32; off > 0; off >>= 1) o2 += __shfl_down(o2, off);
    __shared__ float redo[4];
    if (lane == 0) redo[wid] = o2;
    __syncthreads();
    if (threadIdx.x == 0) {
        float osum = redo[0] + redo[1] + redo[2] + redo[3];
        float og = sqrtf(osum);
        float mterm = -(tr / den[g]);
        atomicAdd(lossws + 0, mterm * (1.f / NGRAPH));
        atomicAdd(lossws + 1, og * (1.f / NGRAPH));
        __threadfence();
        int old = atomicAdd(donecnt, 1);
        if (old == NGRAPH - 1) {
            float l0 = atomicAdd(lossws + 0, 0.f);  // atomic read of the full sum
            float l1 = atomicAdd(lossws + 1, 0.f);
            out[LOSS_OFF + 0] = l0;
            out[LOSS_OFF + 1] = l1;
        }
    }
}

extern "C" void kernel_launch(void* const* d_in, const int* in_sizes, int n_in,
                              void* d_out, int out_size, void* d_ws, size_t ws_size,
                              hipStream_t stream) {
    const float* node_attr = (const float*)d_in[0];
    const float* W = (const float*)d_in[1];
    const float* bias = (const float*)d_in[2];
    const int* edge_index = (const int*)d_in[3];
    int N = in_sizes[0] / F_DIMC;
    int E = in_sizes[3] / 2;
    int perG = N / NGRAPH;
    const int* row = edge_index;
    const int* col = edge_index + E;
    float* out = (float*)d_out;
    char* ws = (char*)d_ws;

    int* hist = (int*)(ws + 0);
    int* cursor = (int*)(ws + 256);
    float* den = (float*)(ws + 512);
    int* donecnt = (int*)(ws + 768);
    float* dense_raw = (float*)(ws + 1024);
    float* ssbuf = (float*)(ws + 66560);
    float* sxbuf = (float*)(ws + 132096);
    float* lossws = (float*)(ws + 394240);
    int* offsets = (int*)(ws + 394496);
    float* sel = (float*)(ws + 394752);
    float* q = (float*)(ws + 6948352);
    uint2* sorted = (uint2*)(ws + 7357952);

    // single memset: hist/cursor/den/donecnt/dense_raw/ssbuf/sxbuf/loss
    hipMemsetAsync(ws, 0, 394496, stream);

    k_sel_hist<<<NB_SEL + NB_HIST, 256, 0, stream>>>(node_attr, W, bias, row, sel, q, hist,
                                                     N, E / 4, perG);
    k_scatter<<<(E + 511) / 512, 512, 0, stream>>>(row, col, q, hist, cursor, offsets, den,
                                                   sorted, E, perG);
    k_adj_sx<<<ADJ_BLOCKS + SX_BLOCKS, 256, 0, stream>>>(sorted, offsets, hist, sel, node_attr,
                                                         dense_raw, ssbuf, sxbuf, perG);
    k_fin<<<NGRAPH, 256, 0, stream>>>(dense_raw, ssbuf, sxbuf, den, lossws, donecnt, out);
}

// Round 9
// 149.377 us; speedup vs baseline: 1.0975x; 1.0975x over previous
//
#include <hip/hip_runtime.h>

#define F_DIMC 64
#define K_DIMC 16
#define NGRAPH 64
#define NXCD 8
#define ADJ_SPLIT 32
#define SX_SPLIT 16
#define NB_SEL 400                         // N/256
#define NB_HIST 256
#define FUSE_BLOCKS 3072                   // per XCD: 256 adj + 128 sx, interleaved 2:1
#define ADJ_OFF (NGRAPH * K_DIMC * F_DIMC)
#define LOSS_OFF (ADJ_OFF + NGRAPH * K_DIMC * K_DIMC)

// ---------------- workspace layout (bytes) ----------------
// zeroed each call: [0, 394496)
//   [0,256)          hist (int[64])
//   [256,512)        cursor (int[64])
//   [512,768)        den (float[64])
//   [768,1024)       donecnt (int) + pad
//   [1024,66560)     dense_raw (float[64*256])
//   [66560,132096)   ssbuf (float[64*256])
//   [132096,394240)  sxbuf (float[64*1024])
//   [394240,394496)  loss (float[2]) + pad
// not zeroed:
//   [394496,394752)    offsets (int[64])   (written by scatter block 0 each call)
//   [394752,6948352)   sel (float[N*16])
//   [6948352,13501952) sorted (uint2[E])

// ---- fused: selection (blocks [0,NB_SEL)) || edge count histogram (rest) ----
__global__ __launch_bounds__(256) void k_sel_hist(const float* __restrict__ node_attr,
                                                  const float* __restrict__ W,
                                                  const float* __restrict__ bias,
                                                  const int* __restrict__ row,
                                                  float* __restrict__ sel,
                                                  int* __restrict__ hist,
                                                  int N, int E4, int perG) {
    __shared__ float sW[K_DIMC][F_DIMC];
    __shared__ float sb[K_DIMC];
    __shared__ int lh[NGRAPH];
    int t = threadIdx.x;
    if (blockIdx.x < NB_SEL) {
        for (int idx = t; idx < F_DIMC * K_DIMC; idx += 256) {
            int f = idx / K_DIMC, k = idx % K_DIMC;
            sW[k][f] = W[idx];
        }
        if (t < K_DIMC) sb[t] = bias[t];
        __syncthreads();
        int n = blockIdx.x * 256 + t;
        if (n >= N) return;

        const float4* xr = (const float4*)(node_attr + (size_t)n * F_DIMC);
        float4 x[F_DIMC / 4];
#pragma unroll
        for (int f4 = 0; f4 < F_DIMC / 4; ++f4) x[f4] = xr[f4];

        float logits[K_DIMC];
#pragma unroll
        for (int k = 0; k < K_DIMC; ++k) {
            const float4* wk = (const float4*)&sW[k][0];
            float acc = sb[k];
#pragma unroll
            for (int f4 = 0; f4 < F_DIMC / 4; ++f4) {
                float4 w = wk[f4];
                acc += x[f4].x * w.x + x[f4].y * w.y + x[f4].z * w.z + x[f4].w * w.w;
            }
            logits[k] = acc;
        }
        float m = logits[0];
#pragma unroll
        for (int k = 1; k < K_DIMC; ++k) m = fmaxf(m, logits[k]);
        float sum = 0.f;
#pragma unroll
        for (int k = 0; k < K_DIMC; ++k) {
            float e = __expf(logits[k] - m);
            logits[k] = e;
            sum += e;
        }
        float inv = 1.f / sum;
        float4* sd = (float4*)(sel + (size_t)n * K_DIMC);
#pragma unroll
        for (int k4 = 0; k4 < K_DIMC / 4; ++k4) {
            float4 v;
            v.x = logits[4 * k4 + 0] * inv;
            v.y = logits[4 * k4 + 1] * inv;
            v.z = logits[4 * k4 + 2] * inv;
            v.w = logits[4 * k4 + 3] * inv;
            sd[k4] = v;
        }
    } else {
        if (t < NGRAPH) lh[t] = 0;
        __syncthreads();
        for (int e4 = (blockIdx.x - NB_SEL) * 256 + t; e4 < E4; e4 += NB_HIST * 256) {
            int4 r4 = ((const int4*)row)[e4];
            atomicAdd(&lh[r4.x / perG], 1);
            atomicAdd(&lh[r4.y / perG], 1);
            atomicAdd(&lh[r4.z / perG], 1);
            atomicAdd(&lh[r4.w / perG], 1);
        }
        __syncthreads();
        if (t < NGRAPH) {
            int c = lh[t];
            if (c) atomicAdd(&hist[t], c);
        }
    }
}

// ---- scatter with in-block scan of hist (no separate scan kernel) ----
__global__ __launch_bounds__(512) void k_scatter(const int* __restrict__ row,
                                                 const int* __restrict__ col,
                                                 const int* __restrict__ hist,
                                                 int* __restrict__ cursor,
                                                 int* __restrict__ offsets,
                                                 uint2* __restrict__ sorted,
                                                 int E, int perG) {
    __shared__ int offs[NGRAPH];
    __shared__ int lcnt[NGRAPH];
    __shared__ int lbase[NGRAPH];
    int t = threadIdx.x;
    if (t < 64) {
        int v = hist[t];
        int sum = v;
#pragma unroll
        for (int d = 1; d < 64; d <<= 1) {
            int o = __shfl_up(sum, d);
            if (t >= d) sum += o;
        }
        offs[t] = sum - v;
        lcnt[t] = 0;
        if (blockIdx.x == 0) offsets[t] = sum - v;
    }
    __syncthreads();
    int e = blockIdx.x * blockDim.x + t;
    int r = 0, c = 0, g = 0, lpos = 0;
    bool valid = e < E;
    if (valid) {
        r = row[e];
        c = col[e];
        g = r / perG;
        lpos = atomicAdd(&lcnt[g], 1);
    }
    __syncthreads();
    if (t < NGRAPH) {
        int cnt = lcnt[t];
        if (cnt) lbase[t] = offs[t] + atomicAdd(&cursor[t], cnt);
    }
    __syncthreads();
    if (valid) {
        sorted[(size_t)lbase[g] + lpos] = make_uint2((unsigned)r, (unsigned)c);
    }
}

// ---- fused adj || SX with per-XCD 2:1 role interleave (co-resident from t=0) ----
// b -> XCD x=b&7, m=b>>3 (0..383/XCD): m%3==2 -> SX (128/XCD), else adj (256/XCD).
// adj: graph g = x*8 + a/32 (a = adj index) -> each graph's sel slice L2-resident.
// den computed FREE in adj: per-lane a^2 summed over lanes = 4*q[row_e].
__global__ __launch_bounds__(256) void k_adj_sx(const uint2* __restrict__ sorted,
                                                const int* __restrict__ offsets,
                                                const int* __restrict__ hist,
                                                const float* __restrict__ sel,
                                                const float* __restrict__ x,
                                                float* __restrict__ dense_raw,
                                                float* __restrict__ ssbuf,
                                                float* __restrict__ sxbuf,
                                                float* __restrict__ den,
                                                int perG) {
    __shared__ union {
        struct { float lacc[4][256]; float qred[4]; } a;
        struct { float lsx[4][K_DIMC * F_DIMC]; float lss[4][256]; } s;
    } u;                                   // 20KB -> 8 blocks/CU
    int b = blockIdx.x;
    int t = threadIdx.x;
    int wid = t >> 6;
    int lane = t & 63;
    int xcd = b & (NXCD - 1);
    int m = b >> 3;                        // 0..383 within this XCD
    if (m % 3 != 2) {
        // ---------------- adj role ----------------
        int a_idx = (m / 3) * 2 + (m % 3); // 0..255
        int g = xcd * (NGRAPH / NXCD) + (a_idx >> 5);
        int split = a_idx & (ADJ_SPLIT - 1);

        int start = offsets[g];
        int cnt = hist[g];
        int wavesPerGraph = ADJ_SPLIT * 4;
        int wseq = split * 4 + wid;
        int i = lane >> 2;
        int j0 = (lane & 3) * 4;

        int chunk = (cnt + wavesPerGraph - 1) / wavesPerGraph;
        int myStart = start + wseq * chunk;
        int myEnd = start + cnt;
        if (myStart + chunk < myEnd) myEnd = myStart + chunk;

        float ax = 0.f, ay = 0.f, az = 0.f, aw = 0.f, qacc = 0.f;
        for (int r0 = myStart; r0 < myEnd; r0 += 64) {
            int nb = myEnd - r0;
            if (nb > 64) nb = 64;
            uint2 pr = sorted[r0 + (lane < nb ? lane : nb - 1)];
            int rx = (int)pr.x * K_DIMC;
            int cx = (int)pr.y * K_DIMC;
#pragma unroll 8
            for (int ee = 0; ee < nb; ++ee) {
                int rb = __builtin_amdgcn_readlane(rx, ee);
                int cb = __builtin_amdgcn_readlane(cx, ee);
                float a = sel[rb + i];
                float4 bv = *(const float4*)(sel + cb + j0);
                ax = fmaf(a, bv.x, ax);
                ay = fmaf(a, bv.y, ay);
                az = fmaf(a, bv.z, az);
                aw = fmaf(a, bv.w, aw);
                qacc = fmaf(a, a, qacc);
            }
        }
        *(float4*)&u.a.lacc[wid][i * K_DIMC + j0] = make_float4(ax, ay, az, aw);
#pragma unroll
        for (int off = 32; off > 0; off >>= 1) qacc += __shfl_down(qacc, off);
        if (lane == 0) u.a.qred[wid] = qacc;
        __syncthreads();
        float s = u.a.lacc[0][t] + u.a.lacc[1][t] + u.a.lacc[2][t] + u.a.lacc[3][t];
        atomicAdd(dense_raw + g * 256 + t, s);
        if (t == 0) {
            float qs = (u.a.qred[0] + u.a.qred[1] + u.a.qred[2] + u.a.qred[3]) * 0.25f;
            atomicAdd(den + g, qs);
        }
    } else {
        // ---------------- SX/SS role ----------------
        int sidx = m / 3;                  // 0..127
        int g = xcd * (NGRAPH / NXCD) + (sidx >> 4);
        int split = sidx & (SX_SPLIT - 1);
        int wslot = split * 4 + wid;       // 0..63
        int k = lane >> 2;
        int sub = lane & 3;
        int f0 = sub * 16;
        int j0 = sub * 4;
        float accss[4] = {0.f, 0.f, 0.f, 0.f};
        float accsx[16];
#pragma unroll
        for (int j = 0; j < 16; ++j) accsx[j] = 0.f;
        size_t base = (size_t)g * perG;
#pragma unroll 2
        for (int nn = wslot; nn < perG; nn += SX_SPLIT * 4) {
            size_t node = base + nn;
            float a = sel[node * K_DIMC + k];
            float4 s4 = *(const float4*)(sel + node * K_DIMC + j0);
            accss[0] += a * s4.x;
            accss[1] += a * s4.y;
            accss[2] += a * s4.z;
            accss[3] += a * s4.w;
            const float4* xv = (const float4*)(x + node * F_DIMC + f0);
#pragma unroll
            for (int j = 0; j < 4; ++j) {
                float4 v = xv[j];
                accsx[4 * j + 0] += a * v.x;
                accsx[4 * j + 1] += a * v.y;
                accsx[4 * j + 2] += a * v.z;
                accsx[4 * j + 3] += a * v.w;
            }
        }
#pragma unroll
        for (int j4 = 0; j4 < 4; ++j4) {
            *(float4*)&u.s.lsx[wid][k * F_DIMC + f0 + 4 * j4] =
                make_float4(accsx[4 * j4], accsx[4 * j4 + 1], accsx[4 * j4 + 2], accsx[4 * j4 + 3]);
        }
        *(float4*)&u.s.lss[wid][k * K_DIMC + j0] = make_float4(accss[0], accss[1], accss[2], accss[3]);
        __syncthreads();
        for (int c2 = t; c2 < K_DIMC * F_DIMC; c2 += 256) {
            float s = u.s.lsx[0][c2] + u.s.lsx[1][c2] + u.s.lsx[2][c2] + u.s.lsx[3][c2];
            atomicAdd(sxbuf + (size_t)g * (K_DIMC * F_DIMC) + c2, s);
        }
        {
            float s = u.s.lss[0][t] + u.s.lss[1][t] + u.s.lss[2][t] + u.s.lss[3][t];
            atomicAdd(ssbuf + g * 256 + t, s);
        }
    }
}

// ---- finalize: normalize adj, copy SX to out, losses via ws + last-block write ----
__global__ __launch_bounds__(256) void k_fin(const float* __restrict__ dense_raw,
                                             const float* __restrict__ ssbuf,
                                             const float* __restrict__ sxbuf,
                                             const float* __restrict__ den,
                                             float* __restrict__ lossws,
                                             int* __restrict__ donecnt,
                                             float* __restrict__ out) {
    int g = blockIdx.x;
    int c = threadIdx.x;
    int k = c >> 4, j = c & 15;
    int lane = threadIdx.x & 63;
    int wid = threadIdx.x >> 6;

    ((float4*)(out + (size_t)g * (K_DIMC * F_DIMC)))[c] =
        ((const float4*)(sxbuf + (size_t)g * (K_DIMC * F_DIMC)))[c];

    float a = dense_raw[g * 256 + c];
    float s = a;
    s += __shfl_xor(s, 1);
    s += __shfl_xor(s, 2);
    s += __shfl_xor(s, 4);
    s += __shfl_xor(s, 8);
    __shared__ float dvrow[K_DIMC];
    if (j == 0) dvrow[k] = sqrtf(s) + 1e-15f;
    __syncthreads();
    float v = a / (dvrow[k] * dvrow[j]);
    out[ADJ_OFF + g * 256 + c] = v;

    float ss = ssbuf[g * 256 + c];
    float tt = (k == j) ? v : 0.f;
    float n2 = ss * ss;
#pragma unroll
    for (int off = 32; off > 0; off >>= 1) {
        tt += __shfl_down(tt, off);
        n2 += __shfl_down(n2, off);
    }
    __shared__ float redt[4], redn[4];
    if (lane == 0) { redt[wid] = tt; redn[wid] = n2; }
    __syncthreads();
    float tr = redt[0] + redt[1] + redt[2] + redt[3];
    float nrm2 = redn[0] + redn[1] + redn[2] + redn[3];
    float invn = 1.f / sqrtf(nrm2);
    float d = ss * invn - ((k == j) ? 0.25f : 0.f);
    float o2 = d * d;
#pragma unroll
    for (int off = 32; off > 0; off >>= 1) o2 += __shfl_down(o2, off);
    __shared__ float redo[4];
    if (lane == 0) redo[wid] = o2;
    __syncthreads();
    if (threadIdx.x == 0) {
        float osum = redo[0] + redo[1] + redo[2] + redo[3];
        float og = sqrtf(osum);
        float mterm = -(tr / den[g]);
        atomicAdd(lossws + 0, mterm * (1.f / NGRAPH));
        atomicAdd(lossws + 1, og * (1.f / NGRAPH));
        __threadfence();
        int old = atomicAdd(donecnt, 1);
        if (old == NGRAPH - 1) {
            float l0 = atomicAdd(lossws + 0, 0.f);
            float l1 = atomicAdd(lossws + 1, 0.f);
            out[LOSS_OFF + 0] = l0;
            out[LOSS_OFF + 1] = l1;
        }
    }
}

extern "C" void kernel_launch(void* const* d_in, const int* in_sizes, int n_in,
                              void* d_out, int out_size, void* d_ws, size_t ws_size,
                              hipStream_t stream) {
    const float* node_attr = (const float*)d_in[0];
    const float* W = (const float*)d_in[1];
    const float* bias = (const float*)d_in[2];
    const int* edge_index = (const int*)d_in[3];
    int N = in_sizes[0] / F_DIMC;
    int E = in_sizes[3] / 2;
    int perG = N / NGRAPH;
    const int* row = edge_index;
    const int* col = edge_index + E;
    float* out = (float*)d_out;
    char* ws = (char*)d_ws;

    int* hist = (int*)(ws + 0);
    int* cursor = (int*)(ws + 256);
    float* den = (float*)(ws + 512);
    int* donecnt = (int*)(ws + 768);
    float* dense_raw = (float*)(ws + 1024);
    float* ssbuf = (float*)(ws + 66560);
    float* sxbuf = (float*)(ws + 132096);
    float* lossws = (float*)(ws + 394240);
    int* offsets = (int*)(ws + 394496);
    float* sel = (float*)(ws + 394752);
    uint2* sorted = (uint2*)(ws + 6948352);

    hipMemsetAsync(ws, 0, 394496, stream);

    k_sel_hist<<<NB_SEL + NB_HIST, 256, 0, stream>>>(node_attr, W, bias, row, sel, hist,
                                                     N, E / 4, perG);
    k_scatter<<<(E + 511) / 512, 512, 0, stream>>>(row, col, hist, cursor, offsets,
                                                   sorted, E, perG);
    k_adj_sx<<<FUSE_BLOCKS, 256, 0, stream>>>(sorted, offsets, hist, sel, node_attr,
                                              dense_raw, ssbuf, sxbuf, den, perG);
    k_fin<<<NGRAPH, 256, 0, stream>>>(dense_raw, ssbuf, sxbuf, den, lossws, donecnt, out);
}